// Round 18
// baseline (269.772 us; speedup 1.0000x reference)
//
#include <hip/hip_runtime.h>
#include <stdint.h>

// H-maxima: 128 iters of m = min(dilate3x3(m), img), marker0 = img - h.
// 8 launches x 16 register-resident iterations, fp16 packed (2 px/word).
// R16-proven config: block 512 thr = 32 groups x 16 segs, 3 rows/thread (W8),
// slab 64 useful + 16 halo each side, 4 slabs/image, 512 blocks = 2/CU,
// conflict-free LDS swizzle sw=seg*12 (LDSS=188), 2 barriers/iter.
// NEW vs R16: horizontal pass via v_max3_f16 + op_sel half-selects --
// 3 VALU/word (2 max3 + 1 pk_min) instead of 5 (2 alignbit + 2 pk_max +
// 1 pk_min): -31% static VALU in the iteration loop.

#define NEGPAIR 0xFBFFFBFFu   // fp16 -65504 x2 == -inf pad
#define TITER 16
#define GROUPS 32
#define LDSS 188              // row stride in words; seg15 span [180,188)

typedef _Float16 h2  __attribute__((ext_vector_type(2)));
typedef __fp16   fh2 __attribute__((ext_vector_type(2)));

static __device__ __forceinline__ uint32_t pmax(uint32_t a, uint32_t b) {
    uint32_t r;
    asm("v_pk_max_f16 %0, %1, %2" : "=v"(r) : "v"(a), "v"(b));
    return r;
}
static __device__ __forceinline__ uint32_t pmin(uint32_t a, uint32_t b) {
    uint32_t r;
    asm("v_pk_min_f16 %0, %1, %2" : "=v"(r) : "v"(a), "v"(b));
    return r;
}
// packed horizontal 3-tap max + mask clamp for one word (2 px):
//   d.lo = max3(prev.hi, cur.lo, cur.hi); d.hi = max3(cur.lo, cur.hi, next.lo)
static __device__ __forceinline__ uint32_t hw3(uint32_t prev, uint32_t cur,
                                               uint32_t next, uint32_t k) {
    uint32_t d;
    asm("v_max3_f16 %0, %1, %2, %2 op_sel:[1,0,1,0]"
        : "=v"(d) : "v"(prev), "v"(cur));
    asm("v_max3_f16 %0, %1, %1, %2 op_sel:[0,1,0,1]"
        : "+v"(d) : "v"(cur), "v"(next));
    return pmin(d, k);
}
static __device__ __forceinline__ uint32_t pack2(float lo, float hi) {
    fh2 p = __builtin_amdgcn_cvt_pkrtz(lo, hi);
    return __builtin_bit_cast(uint32_t, p);
}
// seg s gets seg s-1's word; seg 0 gets NEGPAIR (16-lane DPP row == seg group)
static __device__ __forceinline__ uint32_t dpp_shr1(uint32_t s) {
    return (uint32_t)__builtin_amdgcn_update_dpp((int)NEGPAIR, (int)s, 0x111, 0xF, 0xF, false);
}
// seg s gets seg s+1's word; seg 15 gets NEGPAIR
static __device__ __forceinline__ uint32_t dpp_shl1(uint32_t s) {
    return (uint32_t)__builtin_amdgcn_update_dpp((int)NEGPAIR, (int)s, 0x101, 0xF, 0xF, false);
}

struct W8 { uint32_t s0, s1, s2, s3, s4, s5, s6, s7; };

static __device__ __forceinline__ W8 ld8(const uint32_t* p) {
    uint4 a = reinterpret_cast<const uint4*>(p)[0];
    uint4 b = reinterpret_cast<const uint4*>(p)[1];
    W8 w;
    w.s0 = a.x; w.s1 = a.y; w.s2 = a.z; w.s3 = a.w;
    w.s4 = b.x; w.s5 = b.y; w.s6 = b.z; w.s7 = b.w;
    return w;
}
static __device__ __forceinline__ void st8(uint32_t* p, W8 w) {
    reinterpret_cast<uint4*>(p)[0] = make_uint4(w.s0, w.s1, w.s2, w.s3);
    reinterpret_cast<uint4*>(p)[1] = make_uint4(w.s4, w.s5, w.s6, w.s7);
}
static __device__ __forceinline__ W8 wmax(W8 a, W8 b) {
    W8 r;
    r.s0 = pmax(a.s0, b.s0); r.s1 = pmax(a.s1, b.s1);
    r.s2 = pmax(a.s2, b.s2); r.s3 = pmax(a.s3, b.s3);
    r.s4 = pmax(a.s4, b.s4); r.s5 = pmax(a.s5, b.s5);
    r.s6 = pmax(a.s6, b.s6); r.s7 = pmax(a.s7, b.s7);
    return r;
}
static __device__ __forceinline__ W8 wneg() {
    W8 r;
    r.s0 = NEGPAIR; r.s1 = NEGPAIR; r.s2 = NEGPAIR; r.s3 = NEGPAIR;
    r.s4 = NEGPAIR; r.s5 = NEGPAIR; r.s6 = NEGPAIR; r.s7 = NEGPAIR;
    return r;
}

// horizontal 3-tap max on packed row v, clamped by k: min(hmax3(v), k)
static __device__ __forceinline__ W8 hpass(W8 v, W8 k) {
    uint32_t lv = dpp_shr1(v.s7);
    uint32_t rv = dpp_shl1(v.s0);
    W8 m;
    m.s0 = hw3(lv,   v.s0, v.s1, k.s0);
    m.s1 = hw3(v.s0, v.s1, v.s2, k.s1);
    m.s2 = hw3(v.s1, v.s2, v.s3, k.s2);
    m.s3 = hw3(v.s2, v.s3, v.s4, k.s3);
    m.s4 = hw3(v.s3, v.s4, v.s5, k.s4);
    m.s5 = hw3(v.s4, v.s5, v.s6, k.s5);
    m.s6 = hw3(v.s5, v.s6, v.s7, k.s6);
    m.s7 = hw3(v.s6, v.s7, rv,   k.s7);
    return m;
}

// init: marker = img - h (fp16), maskh = img (fp16). 8 px / thread.
__global__ __launch_bounds__(256) void hx_init(const float* __restrict__ img,
                                               const float* __restrict__ hh,
                                               uint32_t* __restrict__ marker,
                                               uint32_t* __restrict__ maskh) {
    int i = blockIdx.x * 256 + threadIdx.x;
    size_t p0 = (size_t)i * 4;                 // packed index (32768 per image)
    float hb = hh[p0 >> 15];
    const float* src = img + p0 * 2;
    float4 f0 = reinterpret_cast<const float4*>(src)[0];
    float4 f1 = reinterpret_cast<const float4*>(src)[1];
    uint4 km, mk;
    km.x = pack2(f0.x, f0.y);       km.y = pack2(f0.z, f0.w);
    km.z = pack2(f1.x, f1.y);       km.w = pack2(f1.z, f1.w);
    mk.x = pack2(f0.x-hb, f0.y-hb); mk.y = pack2(f0.z-hb, f0.w-hb);
    mk.z = pack2(f1.x-hb, f1.y-hb); mk.w = pack2(f1.z-hb, f1.w-hb);
    *reinterpret_cast<uint4*>(maskh  + p0) = km;
    *reinterpret_cast<uint4*>(marker + p0) = mk;
}

__global__ __launch_bounds__(512, 4) void hx_iter(
    const uint32_t* __restrict__ min_,   // marker in (fp16 packed, 128 words/row)
    const uint32_t* __restrict__ maskh,  // mask (fp16 packed)
    uint32_t*       __restrict__ mout,   // marker out (if !final_out)
    float*          __restrict__ fout,   // f32 out (if final_out)
    int final_out)
{
    // [A=0/B=1][row][word]; A row 0 and B row GROUPS are -inf sentinels
    __shared__ uint32_t H[2][GROUPS + 1][LDSS];   // 49,632 B

    const int tid  = threadIdx.x;
    const int seg  = tid & 15;
    const int g    = tid >> 4;          // 32 groups x 3 rows = 96 staged rows
    const int b    = blockIdx.x >> 2;   // image
    const int slab = blockIdx.x & 3;    // 4 slabs of 64 rows
    const int base = slab * 64 - TITER;
    const int sw   = seg * 12;          // conflict-free, injective, 16B-aligned

    for (int w = tid; w < LDSS; w += 512) {   // sentinels (ordered by 1st barrier)
        H[0][0][w]      = NEGPAIR;
        H[1][GROUPS][w] = NEGPAIR;
    }

    uint32_t* wrA = &H[0][g + 1][sw]; uint32_t* rdA = &H[0][g][sw];
    uint32_t* wrB = &H[1][g][sw];     uint32_t* rdB = &H[1][g + 1][sw];

    W8 m0, m1, m2, k0, k1, k2;
    {
        int ir = base + 3 * g;
        if (ir >= 0 && ir < 256) {
            size_t rp = (((size_t)(b * 256 + ir)) << 7) + seg * 8;
            m0 = ld8(min_ + rp); k0 = ld8(maskh + rp);
        } else { m0 = wneg(); k0 = wneg(); }
        ir++;
        if (ir >= 0 && ir < 256) {
            size_t rp = (((size_t)(b * 256 + ir)) << 7) + seg * 8;
            m1 = ld8(min_ + rp); k1 = ld8(maskh + rp);
        } else { m1 = wneg(); k1 = wneg(); }
        ir++;
        if (ir >= 0 && ir < 256) {
            size_t rp = (((size_t)(b * 256 + ir)) << 7) + seg * 8;
            m2 = ld8(min_ + rp); k2 = ld8(maskh + rp);
        } else { m2 = wneg(); k2 = wneg(); }
    }

    for (int t = 0; t < TITER; ++t) {
        st8(wrB, m0);
        st8(wrA, m2);
        __syncthreads();
        W8 ab = ld8(rdA);
        W8 bl = ld8(rdB);
        W8 t01 = wmax(m0, m1);
        W8 v1  = wmax(t01, m2);
        W8 nm1 = hpass(v1, k1);               // interior row: no halo dep
        W8 v0  = wmax(ab, t01);
        W8 v2  = wmax(wmax(m1, m2), bl);
        __syncthreads();                      // halo consumed; LDS reusable
        m0 = hpass(v0, k0);
        m2 = hpass(v2, k2);
        m1 = nm1;
    }

    // write back useful rows (local rows [TITER, TITER+64))
    #pragma unroll
    for (int r = 0; r < 3; ++r) {
        int local = 3 * g + r;
        if (local >= TITER && local < TITER + 64) {
            int ir = base + local;
            W8 mv = (r == 0) ? m0 : (r == 1) ? m1 : m2;
            if (final_out) {
                float* orow = fout + (((size_t)(b * 256 + ir)) << 8) + seg * 16;
                h2 x, y; float4 f;
                x = __builtin_bit_cast(h2, mv.s0); y = __builtin_bit_cast(h2, mv.s1);
                f.x = (float)x.x; f.y = (float)x.y; f.z = (float)y.x; f.w = (float)y.y;
                reinterpret_cast<float4*>(orow)[0] = f;
                x = __builtin_bit_cast(h2, mv.s2); y = __builtin_bit_cast(h2, mv.s3);
                f.x = (float)x.x; f.y = (float)x.y; f.z = (float)y.x; f.w = (float)y.y;
                reinterpret_cast<float4*>(orow)[1] = f;
                x = __builtin_bit_cast(h2, mv.s4); y = __builtin_bit_cast(h2, mv.s5);
                f.x = (float)x.x; f.y = (float)x.y; f.z = (float)y.x; f.w = (float)y.y;
                reinterpret_cast<float4*>(orow)[2] = f;
                x = __builtin_bit_cast(h2, mv.s6); y = __builtin_bit_cast(h2, mv.s7);
                f.x = (float)x.x; f.y = (float)x.y; f.z = (float)y.x; f.w = (float)y.y;
                reinterpret_cast<float4*>(orow)[3] = f;
            } else {
                uint32_t* orow = mout + (((size_t)(b * 256 + ir)) << 7) + seg * 8;
                st8(orow, mv);
            }
        }
    }
}

extern "C" void kernel_launch(void* const* d_in, const int* in_sizes, int n_in,
                              void* d_out, int out_size, void* d_ws, size_t ws_size,
                              hipStream_t stream) {
    const float* img = (const float*)d_in[0];
    const float* hh  = (const float*)d_in[1];

    uint32_t* pong  = (uint32_t*)d_ws;           // ws[0 : 16.8MB)
    uint32_t* maskh = pong + 4194304;            // ws[16.8 : 33.5MB)
    uint32_t* ping  = (uint32_t*)d_out;          // first 16.8MB of d_out

    hx_init<<<4096, 256, 0, stream>>>(img, hh, ping, maskh);
    // 8 launches x 16 iterations = 128 (ends writing d_out as f32)
    hx_iter<<<512, 512, 0, stream>>>(ping, maskh, pong, nullptr, 0);
    hx_iter<<<512, 512, 0, stream>>>(pong, maskh, ping, nullptr, 0);
    hx_iter<<<512, 512, 0, stream>>>(ping, maskh, pong, nullptr, 0);
    hx_iter<<<512, 512, 0, stream>>>(pong, maskh, ping, nullptr, 0);
    hx_iter<<<512, 512, 0, stream>>>(ping, maskh, pong, nullptr, 0);
    hx_iter<<<512, 512, 0, stream>>>(pong, maskh, ping, nullptr, 0);
    hx_iter<<<512, 512, 0, stream>>>(ping, maskh, pong, nullptr, 0);
    hx_iter<<<512, 512, 0, stream>>>(pong, maskh, nullptr, (float*)d_out, 1);
}

// Round 19
// 198.482 us; speedup vs baseline: 1.3592x; 1.3592x over previous
//
#include <hip/hip_runtime.h>
#include <stdint.h>

// H-maxima: 128 iters of m = min(dilate3x3(m), img), marker0 = img - h.
// 8 launches x 16 register-resident iterations, fp16 packed (2 px/word).
// R16-proven config: block 512 thr = 32 groups x 16 segs, 3 rows/thread (W8),
// slab 64 useful + 16 halo each side, 4 slabs/image, 512 blocks = 2/CU,
// conflict-free LDS swizzle sw=seg*12 (LDSS=188), 2 barriers/iter,
// inline-asm v_pk_max/min_f16 (R16), alignbit horizontal pass (R18's max3 hurt).
// NEW: block-local convergence early-exit. Marker evolution is monotone and
// the staged region evolves autonomously within a launch -> if one full iter
// changes nothing, the remaining in-launch iters are identity => break.
// Check every 4th iter (xor-compare, ~+7% VALU); single LDS flag with
// barrier-separated phases: write 1s at t%4==3 (after B2), tid0 reset at
// t%4==2 (after B2), uniform break-read at t%4==1 (after B1).

#define NEGPAIR 0xFBFFFBFFu   // fp16 -65504 x2 == -inf pad
#define TITER 16
#define GROUPS 32
#define LDSS 188              // row stride in words; seg15 span [180,188)

typedef _Float16 h2  __attribute__((ext_vector_type(2)));
typedef __fp16   fh2 __attribute__((ext_vector_type(2)));

static __device__ __forceinline__ uint32_t pmax(uint32_t a, uint32_t b) {
    uint32_t r;
    asm("v_pk_max_f16 %0, %1, %2" : "=v"(r) : "v"(a), "v"(b));
    return r;
}
static __device__ __forceinline__ uint32_t pmin(uint32_t a, uint32_t b) {
    uint32_t r;
    asm("v_pk_min_f16 %0, %1, %2" : "=v"(r) : "v"(a), "v"(b));
    return r;
}
static __device__ __forceinline__ uint32_t alignb(uint32_t hi, uint32_t lo) {
    return __builtin_amdgcn_alignbit(hi, lo, 16);   // {lo.hi16, hi.lo16}
}
static __device__ __forceinline__ uint32_t pack2(float lo, float hi) {
    fh2 p = __builtin_amdgcn_cvt_pkrtz(lo, hi);
    return __builtin_bit_cast(uint32_t, p);
}
// seg s gets seg s-1's word; seg 0 gets NEGPAIR (16-lane DPP row == seg group)
static __device__ __forceinline__ uint32_t dpp_shr1(uint32_t s) {
    return (uint32_t)__builtin_amdgcn_update_dpp((int)NEGPAIR, (int)s, 0x111, 0xF, 0xF, false);
}
// seg s gets seg s+1's word; seg 15 gets NEGPAIR
static __device__ __forceinline__ uint32_t dpp_shl1(uint32_t s) {
    return (uint32_t)__builtin_amdgcn_update_dpp((int)NEGPAIR, (int)s, 0x101, 0xF, 0xF, false);
}

struct W8 { uint32_t s0, s1, s2, s3, s4, s5, s6, s7; };

static __device__ __forceinline__ W8 ld8(const uint32_t* p) {
    uint4 a = reinterpret_cast<const uint4*>(p)[0];
    uint4 b = reinterpret_cast<const uint4*>(p)[1];
    W8 w;
    w.s0 = a.x; w.s1 = a.y; w.s2 = a.z; w.s3 = a.w;
    w.s4 = b.x; w.s5 = b.y; w.s6 = b.z; w.s7 = b.w;
    return w;
}
static __device__ __forceinline__ void st8(uint32_t* p, W8 w) {
    reinterpret_cast<uint4*>(p)[0] = make_uint4(w.s0, w.s1, w.s2, w.s3);
    reinterpret_cast<uint4*>(p)[1] = make_uint4(w.s4, w.s5, w.s6, w.s7);
}
static __device__ __forceinline__ W8 wmax(W8 a, W8 b) {
    W8 r;
    r.s0 = pmax(a.s0, b.s0); r.s1 = pmax(a.s1, b.s1);
    r.s2 = pmax(a.s2, b.s2); r.s3 = pmax(a.s3, b.s3);
    r.s4 = pmax(a.s4, b.s4); r.s5 = pmax(a.s5, b.s5);
    r.s6 = pmax(a.s6, b.s6); r.s7 = pmax(a.s7, b.s7);
    return r;
}
static __device__ __forceinline__ W8 wneg() {
    W8 r;
    r.s0 = NEGPAIR; r.s1 = NEGPAIR; r.s2 = NEGPAIR; r.s3 = NEGPAIR;
    r.s4 = NEGPAIR; r.s5 = NEGPAIR; r.s6 = NEGPAIR; r.s7 = NEGPAIR;
    return r;
}
static __device__ __forceinline__ uint32_t wdiff(W8 a, W8 b) {
    return (a.s0 ^ b.s0) | (a.s1 ^ b.s1) | (a.s2 ^ b.s2) | (a.s3 ^ b.s3) |
           (a.s4 ^ b.s4) | (a.s5 ^ b.s5) | (a.s6 ^ b.s6) | (a.s7 ^ b.s7);
}

// horizontal 3-tap max on packed row v, clamped by k: min(hmax3(v), k)
static __device__ __forceinline__ W8 hpass(W8 v, W8 k) {
    uint32_t lv = dpp_shr1(v.s7);
    uint32_t rv = dpp_shl1(v.s0);
    W8 m;
    m.s0 = pmin(pmax(pmax(v.s0, alignb(v.s0, lv)),   alignb(v.s1, v.s0)), k.s0);
    m.s1 = pmin(pmax(pmax(v.s1, alignb(v.s1, v.s0)), alignb(v.s2, v.s1)), k.s1);
    m.s2 = pmin(pmax(pmax(v.s2, alignb(v.s2, v.s1)), alignb(v.s3, v.s2)), k.s2);
    m.s3 = pmin(pmax(pmax(v.s3, alignb(v.s3, v.s2)), alignb(v.s4, v.s3)), k.s3);
    m.s4 = pmin(pmax(pmax(v.s4, alignb(v.s4, v.s3)), alignb(v.s5, v.s4)), k.s4);
    m.s5 = pmin(pmax(pmax(v.s5, alignb(v.s5, v.s4)), alignb(v.s6, v.s5)), k.s5);
    m.s6 = pmin(pmax(pmax(v.s6, alignb(v.s6, v.s5)), alignb(v.s7, v.s6)), k.s6);
    m.s7 = pmin(pmax(pmax(v.s7, alignb(v.s7, v.s6)), alignb(rv,   v.s7)), k.s7);
    return m;
}

// init: marker = img - h (fp16), maskh = img (fp16). 8 px / thread.
__global__ __launch_bounds__(256) void hx_init(const float* __restrict__ img,
                                               const float* __restrict__ hh,
                                               uint32_t* __restrict__ marker,
                                               uint32_t* __restrict__ maskh) {
    int i = blockIdx.x * 256 + threadIdx.x;
    size_t p0 = (size_t)i * 4;                 // packed index (32768 per image)
    float hb = hh[p0 >> 15];
    const float* src = img + p0 * 2;
    float4 f0 = reinterpret_cast<const float4*>(src)[0];
    float4 f1 = reinterpret_cast<const float4*>(src)[1];
    uint4 km, mk;
    km.x = pack2(f0.x, f0.y);       km.y = pack2(f0.z, f0.w);
    km.z = pack2(f1.x, f1.y);       km.w = pack2(f1.z, f1.w);
    mk.x = pack2(f0.x-hb, f0.y-hb); mk.y = pack2(f0.z-hb, f0.w-hb);
    mk.z = pack2(f1.x-hb, f1.y-hb); mk.w = pack2(f1.z-hb, f1.w-hb);
    *reinterpret_cast<uint4*>(maskh  + p0) = km;
    *reinterpret_cast<uint4*>(marker + p0) = mk;
}

__global__ __launch_bounds__(512, 4) void hx_iter(
    const uint32_t* __restrict__ min_,   // marker in (fp16 packed, 128 words/row)
    const uint32_t* __restrict__ maskh,  // mask (fp16 packed)
    uint32_t*       __restrict__ mout,   // marker out (if !final_out)
    float*          __restrict__ fout,   // f32 out (if final_out)
    int final_out)
{
    // [A=0/B=1][row][word]; A row 0 and B row GROUPS are -inf sentinels
    __shared__ uint32_t H[2][GROUPS + 1][LDSS];   // 49,632 B
    __shared__ int chflag;

    const int tid  = threadIdx.x;
    const int seg  = tid & 15;
    const int g    = tid >> 4;          // 32 groups x 3 rows = 96 staged rows
    const int b    = blockIdx.x >> 2;   // image
    const int slab = blockIdx.x & 3;    // 4 slabs of 64 rows
    const int base = slab * 64 - TITER;
    const int sw   = seg * 12;          // conflict-free, injective, 16B-aligned

    for (int w = tid; w < LDSS; w += 512) {   // sentinels (ordered by 1st barrier)
        H[0][0][w]      = NEGPAIR;
        H[1][GROUPS][w] = NEGPAIR;
    }
    if (tid == 0) chflag = 1;

    uint32_t* wrA = &H[0][g + 1][sw]; uint32_t* rdA = &H[0][g][sw];
    uint32_t* wrB = &H[1][g][sw];     uint32_t* rdB = &H[1][g + 1][sw];

    W8 m0, m1, m2, k0, k1, k2;
    {
        int ir = base + 3 * g;
        if (ir >= 0 && ir < 256) {
            size_t rp = (((size_t)(b * 256 + ir)) << 7) + seg * 8;
            m0 = ld8(min_ + rp); k0 = ld8(maskh + rp);
        } else { m0 = wneg(); k0 = wneg(); }
        ir++;
        if (ir >= 0 && ir < 256) {
            size_t rp = (((size_t)(b * 256 + ir)) << 7) + seg * 8;
            m1 = ld8(min_ + rp); k1 = ld8(maskh + rp);
        } else { m1 = wneg(); k1 = wneg(); }
        ir++;
        if (ir >= 0 && ir < 256) {
            size_t rp = (((size_t)(b * 256 + ir)) << 7) + seg * 8;
            m2 = ld8(min_ + rp); k2 = ld8(maskh + rp);
        } else { m2 = wneg(); k2 = wneg(); }
    }

    for (int t = 0; t < TITER; ++t) {
        st8(wrB, m0);
        st8(wrA, m2);
        __syncthreads();                      // B1: halo stores + flag visible
        if ((t & 3) == 1 && t > 1 && chflag == 0) break;   // uniform
        W8 ab = ld8(rdA);
        W8 bl = ld8(rdB);
        W8 t01 = wmax(m0, m1);
        W8 v1  = wmax(t01, m2);
        W8 nm1 = hpass(v1, k1);               // interior row: no halo dep
        W8 v0  = wmax(ab, t01);
        W8 v2  = wmax(wmax(m1, m2), bl);
        __syncthreads();                      // B2: halo consumed; LDS reusable
        W8 nm0 = hpass(v0, k0);
        W8 nm2 = hpass(v2, k2);
        if ((t & 3) == 3) {                   // write 1s (racing same value OK)
            uint32_t ch = wdiff(nm0, m0) | wdiff(nm1, m1) | wdiff(nm2, m2);
            if (ch) chflag = 1;
        }
        if (tid == 0 && (t & 3) == 2) chflag = 0;  // reset, barrier-separated
        m0 = nm0; m1 = nm1; m2 = nm2;
    }

    // write back useful rows (local rows [TITER, TITER+64))
    #pragma unroll
    for (int r = 0; r < 3; ++r) {
        int local = 3 * g + r;
        if (local >= TITER && local < TITER + 64) {
            int ir = base + local;
            W8 mv = (r == 0) ? m0 : (r == 1) ? m1 : m2;
            if (final_out) {
                float* orow = fout + (((size_t)(b * 256 + ir)) << 8) + seg * 16;
                h2 x, y; float4 f;
                x = __builtin_bit_cast(h2, mv.s0); y = __builtin_bit_cast(h2, mv.s1);
                f.x = (float)x.x; f.y = (float)x.y; f.z = (float)y.x; f.w = (float)y.y;
                reinterpret_cast<float4*>(orow)[0] = f;
                x = __builtin_bit_cast(h2, mv.s2); y = __builtin_bit_cast(h2, mv.s3);
                f.x = (float)x.x; f.y = (float)x.y; f.z = (float)y.x; f.w = (float)y.y;
                reinterpret_cast<float4*>(orow)[1] = f;
                x = __builtin_bit_cast(h2, mv.s4); y = __builtin_bit_cast(h2, mv.s5);
                f.x = (float)x.x; f.y = (float)x.y; f.z = (float)y.x; f.w = (float)y.y;
                reinterpret_cast<float4*>(orow)[2] = f;
                x = __builtin_bit_cast(h2, mv.s6); y = __builtin_bit_cast(h2, mv.s7);
                f.x = (float)x.x; f.y = (float)x.y; f.z = (float)y.x; f.w = (float)y.y;
                reinterpret_cast<float4*>(orow)[3] = f;
            } else {
                uint32_t* orow = mout + (((size_t)(b * 256 + ir)) << 7) + seg * 8;
                st8(orow, mv);
            }
        }
    }
}

extern "C" void kernel_launch(void* const* d_in, const int* in_sizes, int n_in,
                              void* d_out, int out_size, void* d_ws, size_t ws_size,
                              hipStream_t stream) {
    const float* img = (const float*)d_in[0];
    const float* hh  = (const float*)d_in[1];

    uint32_t* pong  = (uint32_t*)d_ws;           // ws[0 : 16.8MB)
    uint32_t* maskh = pong + 4194304;            // ws[16.8 : 33.5MB)
    uint32_t* ping  = (uint32_t*)d_out;          // first 16.8MB of d_out

    hx_init<<<4096, 256, 0, stream>>>(img, hh, ping, maskh);
    // 8 launches x 16 iterations = 128 (ends writing d_out as f32)
    hx_iter<<<512, 512, 0, stream>>>(ping, maskh, pong, nullptr, 0);
    hx_iter<<<512, 512, 0, stream>>>(pong, maskh, ping, nullptr, 0);
    hx_iter<<<512, 512, 0, stream>>>(ping, maskh, pong, nullptr, 0);
    hx_iter<<<512, 512, 0, stream>>>(pong, maskh, ping, nullptr, 0);
    hx_iter<<<512, 512, 0, stream>>>(ping, maskh, pong, nullptr, 0);
    hx_iter<<<512, 512, 0, stream>>>(pong, maskh, ping, nullptr, 0);
    hx_iter<<<512, 512, 0, stream>>>(ping, maskh, pong, nullptr, 0);
    hx_iter<<<512, 512, 0, stream>>>(pong, maskh, nullptr, (float*)d_out, 1);
}

// Round 20
// 172.972 us; speedup vs baseline: 1.5596x; 1.1475x over previous
//
#include <hip/hip_runtime.h>
#include <stdint.h>

// H-maxima: 128 iters of m = min(dilate3x3(m), img), marker0 = img - h.
// 4 launches x 32 register-resident iterations, fp16 packed (2 px/word).
// R13-proven geometry: 1024 thr = 64 groups x 16 segs, 3 rows/thread (W8),
// slab 128 useful + 32 halo each side (192 staged), 2 slabs/image, 256 blocks
// = 1 block/CU. LDS [2][65][132] = 68.6 KB, seg*8 (R13-proven launchable).
// asm v_pk_max/min_f16 (R16 win). Per-iter early exit via 2-flag ping-pong
// (R19 win, latency 6 -> 2 iters): gen t writes chf[t&1] (P2), resets
// chf[(t+1)&1] (P2), gen t+1 breaks on chf[t&1]==0 after B1. All flag
// accesses barrier-separated; break is uniform.
// vs R19: launches 8 -> 4 => inter-launch traffic 536 -> 268 MB.

#define NEGPAIR 0xFBFFFBFFu   // fp16 -65504 x2 == -inf pad
#define TITER 32
#define GROUPS 64
#define LDSS 132              // row stride in words (R13-proven)

typedef _Float16 h2  __attribute__((ext_vector_type(2)));
typedef __fp16   fh2 __attribute__((ext_vector_type(2)));

static __device__ __forceinline__ uint32_t pmax(uint32_t a, uint32_t b) {
    uint32_t r;
    asm("v_pk_max_f16 %0, %1, %2" : "=v"(r) : "v"(a), "v"(b));
    return r;
}
static __device__ __forceinline__ uint32_t pmin(uint32_t a, uint32_t b) {
    uint32_t r;
    asm("v_pk_min_f16 %0, %1, %2" : "=v"(r) : "v"(a), "v"(b));
    return r;
}
static __device__ __forceinline__ uint32_t alignb(uint32_t hi, uint32_t lo) {
    return __builtin_amdgcn_alignbit(hi, lo, 16);   // {lo.hi16, hi.lo16}
}
static __device__ __forceinline__ uint32_t pack2(float lo, float hi) {
    fh2 p = __builtin_amdgcn_cvt_pkrtz(lo, hi);
    return __builtin_bit_cast(uint32_t, p);
}
// seg s gets seg s-1's word; seg 0 gets NEGPAIR (16-lane DPP row == seg group)
static __device__ __forceinline__ uint32_t dpp_shr1(uint32_t s) {
    return (uint32_t)__builtin_amdgcn_update_dpp((int)NEGPAIR, (int)s, 0x111, 0xF, 0xF, false);
}
// seg s gets seg s+1's word; seg 15 gets NEGPAIR
static __device__ __forceinline__ uint32_t dpp_shl1(uint32_t s) {
    return (uint32_t)__builtin_amdgcn_update_dpp((int)NEGPAIR, (int)s, 0x101, 0xF, 0xF, false);
}

struct W8 { uint32_t s0, s1, s2, s3, s4, s5, s6, s7; };

static __device__ __forceinline__ W8 ld8(const uint32_t* p) {
    uint4 a = reinterpret_cast<const uint4*>(p)[0];
    uint4 b = reinterpret_cast<const uint4*>(p)[1];
    W8 w;
    w.s0 = a.x; w.s1 = a.y; w.s2 = a.z; w.s3 = a.w;
    w.s4 = b.x; w.s5 = b.y; w.s6 = b.z; w.s7 = b.w;
    return w;
}
static __device__ __forceinline__ void st8(uint32_t* p, W8 w) {
    reinterpret_cast<uint4*>(p)[0] = make_uint4(w.s0, w.s1, w.s2, w.s3);
    reinterpret_cast<uint4*>(p)[1] = make_uint4(w.s4, w.s5, w.s6, w.s7);
}
static __device__ __forceinline__ W8 wmax(W8 a, W8 b) {
    W8 r;
    r.s0 = pmax(a.s0, b.s0); r.s1 = pmax(a.s1, b.s1);
    r.s2 = pmax(a.s2, b.s2); r.s3 = pmax(a.s3, b.s3);
    r.s4 = pmax(a.s4, b.s4); r.s5 = pmax(a.s5, b.s5);
    r.s6 = pmax(a.s6, b.s6); r.s7 = pmax(a.s7, b.s7);
    return r;
}
static __device__ __forceinline__ W8 wneg() {
    W8 r;
    r.s0 = NEGPAIR; r.s1 = NEGPAIR; r.s2 = NEGPAIR; r.s3 = NEGPAIR;
    r.s4 = NEGPAIR; r.s5 = NEGPAIR; r.s6 = NEGPAIR; r.s7 = NEGPAIR;
    return r;
}
static __device__ __forceinline__ uint32_t wdiff(W8 a, W8 b) {
    return (a.s0 ^ b.s0) | (a.s1 ^ b.s1) | (a.s2 ^ b.s2) | (a.s3 ^ b.s3) |
           (a.s4 ^ b.s4) | (a.s5 ^ b.s5) | (a.s6 ^ b.s6) | (a.s7 ^ b.s7);
}

// horizontal 3-tap max on packed row v, clamped by k: min(hmax3(v), k)
static __device__ __forceinline__ W8 hpass(W8 v, W8 k) {
    uint32_t lv = dpp_shr1(v.s7);
    uint32_t rv = dpp_shl1(v.s0);
    W8 m;
    m.s0 = pmin(pmax(pmax(v.s0, alignb(v.s0, lv)),   alignb(v.s1, v.s0)), k.s0);
    m.s1 = pmin(pmax(pmax(v.s1, alignb(v.s1, v.s0)), alignb(v.s2, v.s1)), k.s1);
    m.s2 = pmin(pmax(pmax(v.s2, alignb(v.s2, v.s1)), alignb(v.s3, v.s2)), k.s2);
    m.s3 = pmin(pmax(pmax(v.s3, alignb(v.s3, v.s2)), alignb(v.s4, v.s3)), k.s3);
    m.s4 = pmin(pmax(pmax(v.s4, alignb(v.s4, v.s3)), alignb(v.s5, v.s4)), k.s4);
    m.s5 = pmin(pmax(pmax(v.s5, alignb(v.s5, v.s4)), alignb(v.s6, v.s5)), k.s5);
    m.s6 = pmin(pmax(pmax(v.s6, alignb(v.s6, v.s5)), alignb(v.s7, v.s6)), k.s6);
    m.s7 = pmin(pmax(pmax(v.s7, alignb(v.s7, v.s6)), alignb(rv,   v.s7)), k.s7);
    return m;
}

// init: marker = img - h (fp16), maskh = img (fp16). 8 px / thread.
__global__ __launch_bounds__(256) void hx_init(const float* __restrict__ img,
                                               const float* __restrict__ hh,
                                               uint32_t* __restrict__ marker,
                                               uint32_t* __restrict__ maskh) {
    int i = blockIdx.x * 256 + threadIdx.x;
    size_t p0 = (size_t)i * 4;                 // packed index (32768 per image)
    float hb = hh[p0 >> 15];
    const float* src = img + p0 * 2;
    float4 f0 = reinterpret_cast<const float4*>(src)[0];
    float4 f1 = reinterpret_cast<const float4*>(src)[1];
    uint4 km, mk;
    km.x = pack2(f0.x, f0.y);       km.y = pack2(f0.z, f0.w);
    km.z = pack2(f1.x, f1.y);       km.w = pack2(f1.z, f1.w);
    mk.x = pack2(f0.x-hb, f0.y-hb); mk.y = pack2(f0.z-hb, f0.w-hb);
    mk.z = pack2(f1.x-hb, f1.y-hb); mk.w = pack2(f1.z-hb, f1.w-hb);
    *reinterpret_cast<uint4*>(maskh  + p0) = km;
    *reinterpret_cast<uint4*>(marker + p0) = mk;
}

__global__ __launch_bounds__(1024, 1) void hx_iter(
    const uint32_t* __restrict__ min_,   // marker in (fp16 packed, 128 words/row)
    const uint32_t* __restrict__ maskh,  // mask (fp16 packed)
    uint32_t*       __restrict__ mout,   // marker out (if !final_out)
    float*          __restrict__ fout,   // f32 out (if final_out)
    int final_out)
{
    // [A=0/B=1][row][word]; A row 0 and B row GROUPS are -inf sentinels
    __shared__ uint32_t H[2][GROUPS + 1][LDSS];   // 68,640 B (R13-proven)
    __shared__ int chf[2];

    const int tid  = threadIdx.x;
    const int seg  = tid & 15;
    const int g    = tid >> 4;
    const int b    = blockIdx.x >> 1;
    const int slab = blockIdx.x & 1;
    const int base = slab * 128 - TITER;

    if (tid < LDSS) {            // sentinels (ordered by first loop barrier)
        H[0][0][tid]      = NEGPAIR;
        H[1][GROUPS][tid] = NEGPAIR;
    }
    if (tid == 0) { chf[0] = 0; chf[1] = 0; }   // gen0 writes chf[0]

    uint32_t* wrA = &H[0][g + 1][seg * 8]; uint32_t* rdA = &H[0][g][seg * 8];
    uint32_t* wrB = &H[1][g][seg * 8];     uint32_t* rdB = &H[1][g + 1][seg * 8];

    W8 m0, m1, m2, k0, k1, k2;
    {
        int ir = base + 3 * g;
        if (ir >= 0 && ir < 256) {
            size_t rp = (((size_t)(b * 256 + ir)) << 7) + seg * 8;
            m0 = ld8(min_ + rp); k0 = ld8(maskh + rp);
        } else { m0 = wneg(); k0 = wneg(); }
        ir++;
        if (ir >= 0 && ir < 256) {
            size_t rp = (((size_t)(b * 256 + ir)) << 7) + seg * 8;
            m1 = ld8(min_ + rp); k1 = ld8(maskh + rp);
        } else { m1 = wneg(); k1 = wneg(); }
        ir++;
        if (ir >= 0 && ir < 256) {
            size_t rp = (((size_t)(b * 256 + ir)) << 7) + seg * 8;
            m2 = ld8(min_ + rp); k2 = ld8(maskh + rp);
        } else { m2 = wneg(); k2 = wneg(); }
    }

    for (int t = 0; t < TITER; ++t) {
        st8(wrB, m0);
        st8(wrA, m2);
        __syncthreads();                      // B1: halo stores + flags visible
        if (t > 0 && chf[(t - 1) & 1] == 0) break;   // uniform (set in P2(t-1))
        W8 ab = ld8(rdA);
        W8 bl = ld8(rdB);
        W8 t01 = wmax(m0, m1);
        W8 v1  = wmax(t01, m2);
        W8 nm1 = hpass(v1, k1);               // interior row: no halo dep
        W8 v0  = wmax(ab, t01);
        W8 v2  = wmax(wmax(m1, m2), bl);
        __syncthreads();                      // B2: halo consumed; LDS reusable
        W8 nm0 = hpass(v0, k0);
        W8 nm2 = hpass(v2, k2);
        // P2(t): write chf[t&1] (read at B1(t+1)); reset chf[(t+1)&1] (last
        // read before B2(t), next written in P2(t+1)) — all barrier-separated.
        uint32_t ch = wdiff(nm0, m0) | wdiff(nm1, m1) | wdiff(nm2, m2);
        if (ch) chf[t & 1] = 1;
        if (tid == 0) chf[(t + 1) & 1] = 0;
        m0 = nm0; m1 = nm1; m2 = nm2;
    }

    // write back useful rows (local rows [TITER, TITER+128))
    #pragma unroll
    for (int r = 0; r < 3; ++r) {
        int local = 3 * g + r;
        if (local >= TITER && local < TITER + 128) {
            int ir = base + local;
            W8 mv = (r == 0) ? m0 : (r == 1) ? m1 : m2;
            if (final_out) {
                float* orow = fout + (((size_t)(b * 256 + ir)) << 8) + seg * 16;
                h2 x, y; float4 f;
                x = __builtin_bit_cast(h2, mv.s0); y = __builtin_bit_cast(h2, mv.s1);
                f.x = (float)x.x; f.y = (float)x.y; f.z = (float)y.x; f.w = (float)y.y;
                reinterpret_cast<float4*>(orow)[0] = f;
                x = __builtin_bit_cast(h2, mv.s2); y = __builtin_bit_cast(h2, mv.s3);
                f.x = (float)x.x; f.y = (float)x.y; f.z = (float)y.x; f.w = (float)y.y;
                reinterpret_cast<float4*>(orow)[1] = f;
                x = __builtin_bit_cast(h2, mv.s4); y = __builtin_bit_cast(h2, mv.s5);
                f.x = (float)x.x; f.y = (float)x.y; f.z = (float)y.x; f.w = (float)y.y;
                reinterpret_cast<float4*>(orow)[2] = f;
                x = __builtin_bit_cast(h2, mv.s6); y = __builtin_bit_cast(h2, mv.s7);
                f.x = (float)x.x; f.y = (float)x.y; f.z = (float)y.x; f.w = (float)y.y;
                reinterpret_cast<float4*>(orow)[3] = f;
            } else {
                uint32_t* orow = mout + (((size_t)(b * 256 + ir)) << 7) + seg * 8;
                st8(orow, mv);
            }
        }
    }
}

extern "C" void kernel_launch(void* const* d_in, const int* in_sizes, int n_in,
                              void* d_out, int out_size, void* d_ws, size_t ws_size,
                              hipStream_t stream) {
    const float* img = (const float*)d_in[0];
    const float* hh  = (const float*)d_in[1];

    uint32_t* pong  = (uint32_t*)d_ws;           // ws[0 : 16.8MB)
    uint32_t* maskh = pong + 4194304;            // ws[16.8 : 33.5MB)
    uint32_t* ping  = (uint32_t*)d_out;          // first 16.8MB of d_out

    hx_init<<<4096, 256, 0, stream>>>(img, hh, ping, maskh);
    // 4 launches x 32 iterations = 128 (ends writing d_out as f32)
    hx_iter<<<256, 1024, 0, stream>>>(ping, maskh, pong, nullptr, 0);
    hx_iter<<<256, 1024, 0, stream>>>(pong, maskh, ping, nullptr, 0);
    hx_iter<<<256, 1024, 0, stream>>>(ping, maskh, pong, nullptr, 0);
    hx_iter<<<256, 1024, 0, stream>>>(pong, maskh, nullptr, (float*)d_out, 1);
}

// Round 22
// 166.970 us; speedup vs baseline: 1.6157x; 1.0360x over previous
//
#include <hip/hip_runtime.h>
#include <stdint.h>

// H-maxima: 128 iters of m = min(dilate3x3(m), img), marker0 = img - h.
// 4 launches x 32 register-resident iterations, fp16 packed (2 px/word).
// R20 geometry: 1024 thr = 64 groups x 16 segs, 3 rows/thread (W8),
// slab 128 useful + 32 halo each side, 2 slabs/image, 256 blocks = 1/CU.
// ONE barrier/iter via generation-parity double-buffered halo
// (A[2][64][128] + B[2][64][128] = exactly 128 KiB, sentinel-free; boundary
// groups select wneg). Convergence flags in dead rows (B[p][0], A[0][63]),
// 3-slot rotation: iter t writes slot t%3, reads (t+2)%3, resets (t+1)%3.
// FIX vs R21: dropped the odd-group +4 stagger -- seg15's span overflowed
// the 128-word row into the next group's halo (the 0.293 corruption).
// Plain seg*8 offsets; conflicts are known-not-limiting (R15/R20).

#define NEGPAIR 0xFBFFFBFFu   // fp16 -65504 x2 == -inf pad
#define TITER 32
#define GROUPS 64

typedef _Float16 h2  __attribute__((ext_vector_type(2)));
typedef __fp16   fh2 __attribute__((ext_vector_type(2)));

static __device__ __forceinline__ uint32_t pmax(uint32_t a, uint32_t b) {
    uint32_t r;
    asm("v_pk_max_f16 %0, %1, %2" : "=v"(r) : "v"(a), "v"(b));
    return r;
}
static __device__ __forceinline__ uint32_t pmin(uint32_t a, uint32_t b) {
    uint32_t r;
    asm("v_pk_min_f16 %0, %1, %2" : "=v"(r) : "v"(a), "v"(b));
    return r;
}
static __device__ __forceinline__ uint32_t alignb(uint32_t hi, uint32_t lo) {
    return __builtin_amdgcn_alignbit(hi, lo, 16);   // {lo.hi16, hi.lo16}
}
static __device__ __forceinline__ uint32_t pack2(float lo, float hi) {
    fh2 p = __builtin_amdgcn_cvt_pkrtz(lo, hi);
    return __builtin_bit_cast(uint32_t, p);
}
// seg s gets seg s-1's word; seg 0 gets NEGPAIR (16-lane DPP row == seg group)
static __device__ __forceinline__ uint32_t dpp_shr1(uint32_t s) {
    return (uint32_t)__builtin_amdgcn_update_dpp((int)NEGPAIR, (int)s, 0x111, 0xF, 0xF, false);
}
// seg s gets seg s+1's word; seg 15 gets NEGPAIR
static __device__ __forceinline__ uint32_t dpp_shl1(uint32_t s) {
    return (uint32_t)__builtin_amdgcn_update_dpp((int)NEGPAIR, (int)s, 0x101, 0xF, 0xF, false);
}

struct W8 { uint32_t s0, s1, s2, s3, s4, s5, s6, s7; };

static __device__ __forceinline__ W8 ld8(const uint32_t* p) {
    uint4 a = reinterpret_cast<const uint4*>(p)[0];
    uint4 b = reinterpret_cast<const uint4*>(p)[1];
    W8 w;
    w.s0 = a.x; w.s1 = a.y; w.s2 = a.z; w.s3 = a.w;
    w.s4 = b.x; w.s5 = b.y; w.s6 = b.z; w.s7 = b.w;
    return w;
}
static __device__ __forceinline__ void st8(uint32_t* p, W8 w) {
    reinterpret_cast<uint4*>(p)[0] = make_uint4(w.s0, w.s1, w.s2, w.s3);
    reinterpret_cast<uint4*>(p)[1] = make_uint4(w.s4, w.s5, w.s6, w.s7);
}
static __device__ __forceinline__ W8 wmax(W8 a, W8 b) {
    W8 r;
    r.s0 = pmax(a.s0, b.s0); r.s1 = pmax(a.s1, b.s1);
    r.s2 = pmax(a.s2, b.s2); r.s3 = pmax(a.s3, b.s3);
    r.s4 = pmax(a.s4, b.s4); r.s5 = pmax(a.s5, b.s5);
    r.s6 = pmax(a.s6, b.s6); r.s7 = pmax(a.s7, b.s7);
    return r;
}
static __device__ __forceinline__ W8 wneg() {
    W8 r;
    r.s0 = NEGPAIR; r.s1 = NEGPAIR; r.s2 = NEGPAIR; r.s3 = NEGPAIR;
    r.s4 = NEGPAIR; r.s5 = NEGPAIR; r.s6 = NEGPAIR; r.s7 = NEGPAIR;
    return r;
}
static __device__ __forceinline__ uint32_t wdiff(W8 a, W8 b) {
    return (a.s0 ^ b.s0) | (a.s1 ^ b.s1) | (a.s2 ^ b.s2) | (a.s3 ^ b.s3) |
           (a.s4 ^ b.s4) | (a.s5 ^ b.s5) | (a.s6 ^ b.s6) | (a.s7 ^ b.s7);
}

// horizontal 3-tap max on packed row v, clamped by k: min(hmax3(v), k)
static __device__ __forceinline__ W8 hpass(W8 v, W8 k) {
    uint32_t lv = dpp_shr1(v.s7);
    uint32_t rv = dpp_shl1(v.s0);
    W8 m;
    m.s0 = pmin(pmax(pmax(v.s0, alignb(v.s0, lv)),   alignb(v.s1, v.s0)), k.s0);
    m.s1 = pmin(pmax(pmax(v.s1, alignb(v.s1, v.s0)), alignb(v.s2, v.s1)), k.s1);
    m.s2 = pmin(pmax(pmax(v.s2, alignb(v.s2, v.s1)), alignb(v.s3, v.s2)), k.s2);
    m.s3 = pmin(pmax(pmax(v.s3, alignb(v.s3, v.s2)), alignb(v.s4, v.s3)), k.s3);
    m.s4 = pmin(pmax(pmax(v.s4, alignb(v.s4, v.s3)), alignb(v.s5, v.s4)), k.s4);
    m.s5 = pmin(pmax(pmax(v.s5, alignb(v.s5, v.s4)), alignb(v.s6, v.s5)), k.s5);
    m.s6 = pmin(pmax(pmax(v.s6, alignb(v.s6, v.s5)), alignb(v.s7, v.s6)), k.s6);
    m.s7 = pmin(pmax(pmax(v.s7, alignb(v.s7, v.s6)), alignb(rv,   v.s7)), k.s7);
    return m;
}

// init: marker = img - h (fp16), maskh = img (fp16). 8 px / thread.
__global__ __launch_bounds__(256) void hx_init(const float* __restrict__ img,
                                               const float* __restrict__ hh,
                                               uint32_t* __restrict__ marker,
                                               uint32_t* __restrict__ maskh) {
    int i = blockIdx.x * 256 + threadIdx.x;
    size_t p0 = (size_t)i * 4;                 // packed index (32768 per image)
    float hb = hh[p0 >> 15];
    const float* src = img + p0 * 2;
    float4 f0 = reinterpret_cast<const float4*>(src)[0];
    float4 f1 = reinterpret_cast<const float4*>(src)[1];
    uint4 km, mk;
    km.x = pack2(f0.x, f0.y);       km.y = pack2(f0.z, f0.w);
    km.z = pack2(f1.x, f1.y);       km.w = pack2(f1.z, f1.w);
    mk.x = pack2(f0.x-hb, f0.y-hb); mk.y = pack2(f0.z-hb, f0.w-hb);
    mk.z = pack2(f1.x-hb, f1.y-hb); mk.w = pack2(f1.z-hb, f1.w-hb);
    *reinterpret_cast<uint4*>(maskh  + p0) = km;
    *reinterpret_cast<uint4*>(marker + p0) = mk;
}

__global__ __launch_bounds__(1024, 1) void hx_iter(
    const uint32_t* __restrict__ min_,   // marker in (fp16 packed, 128 words/row)
    const uint32_t* __restrict__ maskh,  // mask (fp16 packed)
    uint32_t*       __restrict__ mout,   // marker out (if !final_out)
    float*          __restrict__ fout,   // f32 out (if final_out)
    int final_out)
{
    // Parity halo buffers, sentinel-free. A[p][g] = g's m2 (read by g+1);
    // B[p][g] = g's m0 (read by g-1). B[p][0] and A[p][63] are dead rows
    // (writes skipped) -> host the 3 convergence-flag slots.
    __shared__ uint32_t A[2][GROUPS][128];   // 65,536 B
    __shared__ uint32_t B[2][GROUPS][128];   // 65,536 B  (total exactly 128 KiB)

    const int tid  = threadIdx.x;
    const int seg  = tid & 15;
    const int g    = tid >> 4;
    const int b    = blockIdx.x >> 1;
    const int slab = blockIdx.x & 1;
    const int base = slab * 128 - TITER;
    const int sw   = seg * 8;            // plain offsets; no stagger (R21 bug)

    uint32_t* f0p = &B[0][0][0];
    uint32_t* f1p = &B[1][0][0];
    uint32_t* f2p = &A[0][GROUPS - 1][0];
    if (tid == 0) { *f0p = 0; *f1p = 0; *f2p = 0; }
    uint32_t *pW = f0p, *pR = f2p, *pZ = f1p;   // t=0: write s0, read s2, reset s1

    W8 m0, m1, m2, k0, k1, k2;
    {
        int ir = base + 3 * g;
        if (ir >= 0 && ir < 256) {
            size_t rp = (((size_t)(b * 256 + ir)) << 7) + seg * 8;
            m0 = ld8(min_ + rp); k0 = ld8(maskh + rp);
        } else { m0 = wneg(); k0 = wneg(); }
        ir++;
        if (ir >= 0 && ir < 256) {
            size_t rp = (((size_t)(b * 256 + ir)) << 7) + seg * 8;
            m1 = ld8(min_ + rp); k1 = ld8(maskh + rp);
        } else { m1 = wneg(); k1 = wneg(); }
        ir++;
        if (ir >= 0 && ir < 256) {
            size_t rp = (((size_t)(b * 256 + ir)) << 7) + seg * 8;
            m2 = ld8(min_ + rp); k2 = ld8(maskh + rp);
        } else { m2 = wneg(); k2 = wneg(); }
    }

    for (int t = 0; t < TITER; ++t) {
        const int p = t & 1;
        if (g < GROUPS - 1) st8(&A[p][g][sw], m2);   // A[p][63] = flag home
        if (g > 0)          st8(&B[p][g][sw], m0);   // B[p][0]  = flag home
        __syncthreads();                              // the ONLY barrier/iter
        if (t > 0 && *pR == 0) break;                 // uniform
        W8 ab = (g > 0)          ? ld8(&A[p][g - 1][sw]) : wneg();
        W8 bl = (g < GROUPS - 1) ? ld8(&B[p][g + 1][sw]) : wneg();
        W8 t01 = wmax(m0, m1);
        W8 v1  = wmax(t01, m2);
        W8 nm1 = hpass(v1, k1);               // interior row: no halo dep
        W8 v0  = wmax(ab, t01);
        W8 v2  = wmax(wmax(m1, m2), bl);
        W8 nm0 = hpass(v0, k0);
        W8 nm2 = hpass(v2, k2);
        uint32_t ch = wdiff(nm0, m0) | wdiff(nm1, m1) | wdiff(nm2, m2);
        if (ch) *pW = 1;                      // racing 1s, uniform addr: OK
        if (tid == 0) *pZ = 0;                // slot (t+1)%3, next written t+1
        uint32_t* tp = pW; pW = pZ; pZ = pR; pR = tp;   // rotate slots
        m0 = nm0; m1 = nm1; m2 = nm2;
    }

    // write back useful rows (local rows [TITER, TITER+128))
    #pragma unroll
    for (int r = 0; r < 3; ++r) {
        int local = 3 * g + r;
        if (local >= TITER && local < TITER + 128) {
            int ir = base + local;
            W8 mv = (r == 0) ? m0 : (r == 1) ? m1 : m2;
            if (final_out) {
                float* orow = fout + (((size_t)(b * 256 + ir)) << 8) + seg * 16;
                h2 x, y; float4 f;
                x = __builtin_bit_cast(h2, mv.s0); y = __builtin_bit_cast(h2, mv.s1);
                f.x = (float)x.x; f.y = (float)x.y; f.z = (float)y.x; f.w = (float)y.y;
                reinterpret_cast<float4*>(orow)[0] = f;
                x = __builtin_bit_cast(h2, mv.s2); y = __builtin_bit_cast(h2, mv.s3);
                f.x = (float)x.x; f.y = (float)x.y; f.z = (float)y.x; f.w = (float)y.y;
                reinterpret_cast<float4*>(orow)[1] = f;
                x = __builtin_bit_cast(h2, mv.s4); y = __builtin_bit_cast(h2, mv.s5);
                f.x = (float)x.x; f.y = (float)x.y; f.z = (float)y.x; f.w = (float)y.y;
                reinterpret_cast<float4*>(orow)[2] = f;
                x = __builtin_bit_cast(h2, mv.s6); y = __builtin_bit_cast(h2, mv.s7);
                f.x = (float)x.x; f.y = (float)x.y; f.z = (float)y.x; f.w = (float)y.y;
                reinterpret_cast<float4*>(orow)[3] = f;
            } else {
                uint32_t* orow = mout + (((size_t)(b * 256 + ir)) << 7) + seg * 8;
                st8(orow, mv);
            }
        }
    }
}

extern "C" void kernel_launch(void* const* d_in, const int* in_sizes, int n_in,
                              void* d_out, int out_size, void* d_ws, size_t ws_size,
                              hipStream_t stream) {
    const float* img = (const float*)d_in[0];
    const float* hh  = (const float*)d_in[1];

    uint32_t* pong  = (uint32_t*)d_ws;           // ws[0 : 16.8MB)
    uint32_t* maskh = pong + 4194304;            // ws[16.8 : 33.5MB)
    uint32_t* ping  = (uint32_t*)d_out;          // first 16.8MB of d_out

    hx_init<<<4096, 256, 0, stream>>>(img, hh, ping, maskh);
    // 4 launches x 32 iterations = 128 (ends writing d_out as f32)
    hx_iter<<<256, 1024, 0, stream>>>(ping, maskh, pong, nullptr, 0);
    hx_iter<<<256, 1024, 0, stream>>>(pong, maskh, ping, nullptr, 0);
    hx_iter<<<256, 1024, 0, stream>>>(ping, maskh, pong, nullptr, 0);
    hx_iter<<<256, 1024, 0, stream>>>(pong, maskh, nullptr, (float*)d_out, 1);
}

// Round 23
// 159.574 us; speedup vs baseline: 1.6906x; 1.0463x over previous
//
#include <hip/hip_runtime.h>
#include <stdint.h>

// H-maxima: 128 iters of m = min(dilate3x3(m), img), marker0 = img - h.
// 4 launches x 32 register-resident iterations, fp16 packed (2 px/word).
// 1024 thr = 64 groups x 16 segs, 3 rows/thread (W8), slab 128 useful +
// 32 halo each side, 2 slabs/image, 256 blocks = 1/CU.
// ONE barrier/iter via generation-parity double-buffered halo (128 KiB LDS),
// flags in dead halo rows, 3-slot rotation (R22-proven).
// NEW vs R22: init FUSED into launch 1 (init_mode): loads img f32, computes
// packed mask + marker (img-h) in-register, writes maskh for later launches.
// Eliminates the hx_init dispatch + marker init write/read (~33 MB).

#define NEGPAIR 0xFBFFFBFFu   // fp16 -65504 x2 == -inf pad
#define TITER 32
#define GROUPS 64

typedef _Float16 h2  __attribute__((ext_vector_type(2)));
typedef __fp16   fh2 __attribute__((ext_vector_type(2)));

static __device__ __forceinline__ uint32_t pmax(uint32_t a, uint32_t b) {
    uint32_t r;
    asm("v_pk_max_f16 %0, %1, %2" : "=v"(r) : "v"(a), "v"(b));
    return r;
}
static __device__ __forceinline__ uint32_t pmin(uint32_t a, uint32_t b) {
    uint32_t r;
    asm("v_pk_min_f16 %0, %1, %2" : "=v"(r) : "v"(a), "v"(b));
    return r;
}
static __device__ __forceinline__ uint32_t alignb(uint32_t hi, uint32_t lo) {
    return __builtin_amdgcn_alignbit(hi, lo, 16);   // {lo.hi16, hi.lo16}
}
static __device__ __forceinline__ uint32_t pack2(float lo, float hi) {
    fh2 p = __builtin_amdgcn_cvt_pkrtz(lo, hi);
    return __builtin_bit_cast(uint32_t, p);
}
// seg s gets seg s-1's word; seg 0 gets NEGPAIR (16-lane DPP row == seg group)
static __device__ __forceinline__ uint32_t dpp_shr1(uint32_t s) {
    return (uint32_t)__builtin_amdgcn_update_dpp((int)NEGPAIR, (int)s, 0x111, 0xF, 0xF, false);
}
// seg s gets seg s+1's word; seg 15 gets NEGPAIR
static __device__ __forceinline__ uint32_t dpp_shl1(uint32_t s) {
    return (uint32_t)__builtin_amdgcn_update_dpp((int)NEGPAIR, (int)s, 0x101, 0xF, 0xF, false);
}

struct W8 { uint32_t s0, s1, s2, s3, s4, s5, s6, s7; };

static __device__ __forceinline__ W8 ld8(const uint32_t* p) {
    uint4 a = reinterpret_cast<const uint4*>(p)[0];
    uint4 b = reinterpret_cast<const uint4*>(p)[1];
    W8 w;
    w.s0 = a.x; w.s1 = a.y; w.s2 = a.z; w.s3 = a.w;
    w.s4 = b.x; w.s5 = b.y; w.s6 = b.z; w.s7 = b.w;
    return w;
}
static __device__ __forceinline__ void st8(uint32_t* p, W8 w) {
    reinterpret_cast<uint4*>(p)[0] = make_uint4(w.s0, w.s1, w.s2, w.s3);
    reinterpret_cast<uint4*>(p)[1] = make_uint4(w.s4, w.s5, w.s6, w.s7);
}
static __device__ __forceinline__ W8 wmax(W8 a, W8 b) {
    W8 r;
    r.s0 = pmax(a.s0, b.s0); r.s1 = pmax(a.s1, b.s1);
    r.s2 = pmax(a.s2, b.s2); r.s3 = pmax(a.s3, b.s3);
    r.s4 = pmax(a.s4, b.s4); r.s5 = pmax(a.s5, b.s5);
    r.s6 = pmax(a.s6, b.s6); r.s7 = pmax(a.s7, b.s7);
    return r;
}
static __device__ __forceinline__ W8 wneg() {
    W8 r;
    r.s0 = NEGPAIR; r.s1 = NEGPAIR; r.s2 = NEGPAIR; r.s3 = NEGPAIR;
    r.s4 = NEGPAIR; r.s5 = NEGPAIR; r.s6 = NEGPAIR; r.s7 = NEGPAIR;
    return r;
}
static __device__ __forceinline__ uint32_t wdiff(W8 a, W8 b) {
    return (a.s0 ^ b.s0) | (a.s1 ^ b.s1) | (a.s2 ^ b.s2) | (a.s3 ^ b.s3) |
           (a.s4 ^ b.s4) | (a.s5 ^ b.s5) | (a.s6 ^ b.s6) | (a.s7 ^ b.s7);
}

// horizontal 3-tap max on packed row v, clamped by k: min(hmax3(v), k)
static __device__ __forceinline__ W8 hpass(W8 v, W8 k) {
    uint32_t lv = dpp_shr1(v.s7);
    uint32_t rv = dpp_shl1(v.s0);
    W8 m;
    m.s0 = pmin(pmax(pmax(v.s0, alignb(v.s0, lv)),   alignb(v.s1, v.s0)), k.s0);
    m.s1 = pmin(pmax(pmax(v.s1, alignb(v.s1, v.s0)), alignb(v.s2, v.s1)), k.s1);
    m.s2 = pmin(pmax(pmax(v.s2, alignb(v.s2, v.s1)), alignb(v.s3, v.s2)), k.s2);
    m.s3 = pmin(pmax(pmax(v.s3, alignb(v.s3, v.s2)), alignb(v.s4, v.s3)), k.s3);
    m.s4 = pmin(pmax(pmax(v.s4, alignb(v.s4, v.s3)), alignb(v.s5, v.s4)), k.s4);
    m.s5 = pmin(pmax(pmax(v.s5, alignb(v.s5, v.s4)), alignb(v.s6, v.s5)), k.s5);
    m.s6 = pmin(pmax(pmax(v.s6, alignb(v.s6, v.s5)), alignb(v.s7, v.s6)), k.s6);
    m.s7 = pmin(pmax(pmax(v.s7, alignb(v.s7, v.s6)), alignb(rv,   v.s7)), k.s7);
    return m;
}

__global__ __launch_bounds__(1024, 1) void hx_iter(
    const uint32_t* __restrict__ min_,   // marker in (ignored if init_mode)
    uint32_t*       __restrict__ maskh,  // mask fp16 (written if init_mode)
    uint32_t*       __restrict__ mout,   // marker out (if !final_out)
    float*          __restrict__ fout,   // f32 out (if final_out)
    const float*    __restrict__ img,    // f32 img (init_mode only)
    const float*    __restrict__ hh,     // h per image (init_mode only)
    int init_mode, int final_out)
{
    // Parity halo buffers, sentinel-free. A[p][g] = g's m2 (read by g+1);
    // B[p][g] = g's m0 (read by g-1). B[p][0] and A[p][63] are dead rows
    // (writes skipped) -> host the 3 convergence-flag slots.
    __shared__ uint32_t A[2][GROUPS][128];   // 65,536 B
    __shared__ uint32_t B[2][GROUPS][128];   // 65,536 B  (total exactly 128 KiB)

    const int tid  = threadIdx.x;
    const int seg  = tid & 15;
    const int g    = tid >> 4;
    const int b    = blockIdx.x >> 1;
    const int slab = blockIdx.x & 1;
    const int base = slab * 128 - TITER;
    const int sw   = seg * 8;

    uint32_t* f0p = &B[0][0][0];
    uint32_t* f1p = &B[1][0][0];
    uint32_t* f2p = &A[0][GROUPS - 1][0];
    if (tid == 0) { *f0p = 0; *f1p = 0; *f2p = 0; }
    uint32_t *pW = f0p, *pR = f2p, *pZ = f1p;   // t=0: write s0, read s2, reset s1

    W8 m0, m1, m2, k0, k1, k2;
    if (init_mode) {
        float hb = hh[b];
        #pragma unroll
        for (int r = 0; r < 3; ++r) {
            int ir = base + 3 * g + r;
            W8 mv, kv;
            if (ir >= 0 && ir < 256) {
                size_t rowf = (((size_t)(b * 256 + ir)) << 8) + seg * 16;
                const float4* src = reinterpret_cast<const float4*>(img + rowf);
                float4 fa = src[0], fb = src[1], fc = src[2], fd = src[3];
                kv.s0 = pack2(fa.x, fa.y);       kv.s1 = pack2(fa.z, fa.w);
                kv.s2 = pack2(fb.x, fb.y);       kv.s3 = pack2(fb.z, fb.w);
                kv.s4 = pack2(fc.x, fc.y);       kv.s5 = pack2(fc.z, fc.w);
                kv.s6 = pack2(fd.x, fd.y);       kv.s7 = pack2(fd.z, fd.w);
                mv.s0 = pack2(fa.x-hb, fa.y-hb); mv.s1 = pack2(fa.z-hb, fa.w-hb);
                mv.s2 = pack2(fb.x-hb, fb.y-hb); mv.s3 = pack2(fb.z-hb, fb.w-hb);
                mv.s4 = pack2(fc.x-hb, fc.y-hb); mv.s5 = pack2(fc.z-hb, fc.w-hb);
                mv.s6 = pack2(fd.x-hb, fd.y-hb); mv.s7 = pack2(fd.z-hb, fd.w-hb);
                size_t rp = (((size_t)(b * 256 + ir)) << 7) + seg * 8;
                st8(maskh + rp, kv);   // dup writes in overlap regions: same data
            } else { mv = wneg(); kv = wneg(); }
            if (r == 0) { m0 = mv; k0 = kv; }
            else if (r == 1) { m1 = mv; k1 = kv; }
            else { m2 = mv; k2 = kv; }
        }
    } else {
        int ir = base + 3 * g;
        if (ir >= 0 && ir < 256) {
            size_t rp = (((size_t)(b * 256 + ir)) << 7) + seg * 8;
            m0 = ld8(min_ + rp); k0 = ld8(maskh + rp);
        } else { m0 = wneg(); k0 = wneg(); }
        ir++;
        if (ir >= 0 && ir < 256) {
            size_t rp = (((size_t)(b * 256 + ir)) << 7) + seg * 8;
            m1 = ld8(min_ + rp); k1 = ld8(maskh + rp);
        } else { m1 = wneg(); k1 = wneg(); }
        ir++;
        if (ir >= 0 && ir < 256) {
            size_t rp = (((size_t)(b * 256 + ir)) << 7) + seg * 8;
            m2 = ld8(min_ + rp); k2 = ld8(maskh + rp);
        } else { m2 = wneg(); k2 = wneg(); }
    }

    for (int t = 0; t < TITER; ++t) {
        const int p = t & 1;
        if (g < GROUPS - 1) st8(&A[p][g][sw], m2);   // A[p][63] = flag home
        if (g > 0)          st8(&B[p][g][sw], m0);   // B[p][0]  = flag home
        __syncthreads();                              // the ONLY barrier/iter
        if (t > 0 && *pR == 0) break;                 // uniform
        W8 ab = (g > 0)          ? ld8(&A[p][g - 1][sw]) : wneg();
        W8 bl = (g < GROUPS - 1) ? ld8(&B[p][g + 1][sw]) : wneg();
        W8 t01 = wmax(m0, m1);
        W8 v1  = wmax(t01, m2);
        W8 nm1 = hpass(v1, k1);               // interior row: no halo dep
        W8 v0  = wmax(ab, t01);
        W8 v2  = wmax(wmax(m1, m2), bl);
        W8 nm0 = hpass(v0, k0);
        W8 nm2 = hpass(v2, k2);
        uint32_t ch = wdiff(nm0, m0) | wdiff(nm1, m1) | wdiff(nm2, m2);
        if (ch) *pW = 1;                      // racing 1s, uniform addr: OK
        if (tid == 0) *pZ = 0;                // slot (t+1)%3, next written t+1
        uint32_t* tp = pW; pW = pZ; pZ = pR; pR = tp;   // rotate slots
        m0 = nm0; m1 = nm1; m2 = nm2;
    }

    // write back useful rows (local rows [TITER, TITER+128))
    #pragma unroll
    for (int r = 0; r < 3; ++r) {
        int local = 3 * g + r;
        if (local >= TITER && local < TITER + 128) {
            int ir = base + local;
            W8 mv = (r == 0) ? m0 : (r == 1) ? m1 : m2;
            if (final_out) {
                float* orow = fout + (((size_t)(b * 256 + ir)) << 8) + seg * 16;
                h2 x, y; float4 f;
                x = __builtin_bit_cast(h2, mv.s0); y = __builtin_bit_cast(h2, mv.s1);
                f.x = (float)x.x; f.y = (float)x.y; f.z = (float)y.x; f.w = (float)y.y;
                reinterpret_cast<float4*>(orow)[0] = f;
                x = __builtin_bit_cast(h2, mv.s2); y = __builtin_bit_cast(h2, mv.s3);
                f.x = (float)x.x; f.y = (float)x.y; f.z = (float)y.x; f.w = (float)y.y;
                reinterpret_cast<float4*>(orow)[1] = f;
                x = __builtin_bit_cast(h2, mv.s4); y = __builtin_bit_cast(h2, mv.s5);
                f.x = (float)x.x; f.y = (float)x.y; f.z = (float)y.x; f.w = (float)y.y;
                reinterpret_cast<float4*>(orow)[2] = f;
                x = __builtin_bit_cast(h2, mv.s6); y = __builtin_bit_cast(h2, mv.s7);
                f.x = (float)x.x; f.y = (float)x.y; f.z = (float)y.x; f.w = (float)y.y;
                reinterpret_cast<float4*>(orow)[3] = f;
            } else {
                uint32_t* orow = mout + (((size_t)(b * 256 + ir)) << 7) + seg * 8;
                st8(orow, mv);
            }
        }
    }
}

extern "C" void kernel_launch(void* const* d_in, const int* in_sizes, int n_in,
                              void* d_out, int out_size, void* d_ws, size_t ws_size,
                              hipStream_t stream) {
    const float* img = (const float*)d_in[0];
    const float* hh  = (const float*)d_in[1];

    uint32_t* pong  = (uint32_t*)d_ws;           // ws[0 : 16.8MB)
    uint32_t* maskh = pong + 4194304;            // ws[16.8 : 33.5MB)
    uint32_t* ping  = (uint32_t*)d_out;          // first 16.8MB of d_out

    // 4 launches x 32 iterations = 128; launch 1 fuses init (img-h, maskh).
    hx_iter<<<256, 1024, 0, stream>>>(nullptr, maskh, pong, nullptr, img, hh, 1, 0);
    hx_iter<<<256, 1024, 0, stream>>>(pong, maskh, ping, nullptr, nullptr, nullptr, 0, 0);
    hx_iter<<<256, 1024, 0, stream>>>(ping, maskh, pong, nullptr, nullptr, nullptr, 0, 0);
    hx_iter<<<256, 1024, 0, stream>>>(pong, maskh, nullptr, (float*)d_out, nullptr, nullptr, 0, 1);
}

// Round 24
// 148.923 us; speedup vs baseline: 1.8115x; 1.0715x over previous
//
#include <hip/hip_runtime.h>
#include <stdint.h>

// H-maxima: 128 iters of m = min(dilate3x3(m), img), marker0 = img - h.
// SINGLE LAUNCH: one block per image (B=128 blocks x 1024 thr), 64 groups x
// 4 rows/thread = all 256 rows staged in registers -- NO halo, NO redundancy,
// NO inter-launch traffic (mask stays in registers; d_ws unused).
// TITER=128 with per-iter block-local early exit (exact: converged => identity).
// ONE barrier/iter via generation-parity double-buffered halo rows
// (A[2][64][128] + B[2][64][128] = exactly 128 KiB, R22/R23-proven).
// Convergence flags in dead rows (B[p][0], A[0][63]), 3-slot rotation:
// iter t writes slot t%3, reads (t+2)%3, resets (t+1)%3 (R22-proven).
// asm v_pk_max/min_f16 + alignbit + DPP seg-edge (R16-proven primitives).

#define NEGPAIR 0xFBFFFBFFu   // fp16 -65504 x2 == -inf pad
#define TITER 128
#define GROUPS 64

typedef _Float16 h2  __attribute__((ext_vector_type(2)));
typedef __fp16   fh2 __attribute__((ext_vector_type(2)));

static __device__ __forceinline__ uint32_t pmax(uint32_t a, uint32_t b) {
    uint32_t r;
    asm("v_pk_max_f16 %0, %1, %2" : "=v"(r) : "v"(a), "v"(b));
    return r;
}
static __device__ __forceinline__ uint32_t pmin(uint32_t a, uint32_t b) {
    uint32_t r;
    asm("v_pk_min_f16 %0, %1, %2" : "=v"(r) : "v"(a), "v"(b));
    return r;
}
static __device__ __forceinline__ uint32_t alignb(uint32_t hi, uint32_t lo) {
    return __builtin_amdgcn_alignbit(hi, lo, 16);   // {lo.hi16, hi.lo16}
}
static __device__ __forceinline__ uint32_t pack2(float lo, float hi) {
    fh2 p = __builtin_amdgcn_cvt_pkrtz(lo, hi);
    return __builtin_bit_cast(uint32_t, p);
}
// seg s gets seg s-1's word; seg 0 gets NEGPAIR (16-lane DPP row == seg group)
static __device__ __forceinline__ uint32_t dpp_shr1(uint32_t s) {
    return (uint32_t)__builtin_amdgcn_update_dpp((int)NEGPAIR, (int)s, 0x111, 0xF, 0xF, false);
}
// seg s gets seg s+1's word; seg 15 gets NEGPAIR
static __device__ __forceinline__ uint32_t dpp_shl1(uint32_t s) {
    return (uint32_t)__builtin_amdgcn_update_dpp((int)NEGPAIR, (int)s, 0x101, 0xF, 0xF, false);
}

struct W8 { uint32_t s0, s1, s2, s3, s4, s5, s6, s7; };

static __device__ __forceinline__ W8 ld8(const uint32_t* p) {
    uint4 a = reinterpret_cast<const uint4*>(p)[0];
    uint4 b = reinterpret_cast<const uint4*>(p)[1];
    W8 w;
    w.s0 = a.x; w.s1 = a.y; w.s2 = a.z; w.s3 = a.w;
    w.s4 = b.x; w.s5 = b.y; w.s6 = b.z; w.s7 = b.w;
    return w;
}
static __device__ __forceinline__ void st8(uint32_t* p, W8 w) {
    reinterpret_cast<uint4*>(p)[0] = make_uint4(w.s0, w.s1, w.s2, w.s3);
    reinterpret_cast<uint4*>(p)[1] = make_uint4(w.s4, w.s5, w.s6, w.s7);
}
static __device__ __forceinline__ W8 wmax(W8 a, W8 b) {
    W8 r;
    r.s0 = pmax(a.s0, b.s0); r.s1 = pmax(a.s1, b.s1);
    r.s2 = pmax(a.s2, b.s2); r.s3 = pmax(a.s3, b.s3);
    r.s4 = pmax(a.s4, b.s4); r.s5 = pmax(a.s5, b.s5);
    r.s6 = pmax(a.s6, b.s6); r.s7 = pmax(a.s7, b.s7);
    return r;
}
static __device__ __forceinline__ W8 wneg() {
    W8 r;
    r.s0 = NEGPAIR; r.s1 = NEGPAIR; r.s2 = NEGPAIR; r.s3 = NEGPAIR;
    r.s4 = NEGPAIR; r.s5 = NEGPAIR; r.s6 = NEGPAIR; r.s7 = NEGPAIR;
    return r;
}
static __device__ __forceinline__ uint32_t wdiff(W8 a, W8 b) {
    return (a.s0 ^ b.s0) | (a.s1 ^ b.s1) | (a.s2 ^ b.s2) | (a.s3 ^ b.s3) |
           (a.s4 ^ b.s4) | (a.s5 ^ b.s5) | (a.s6 ^ b.s6) | (a.s7 ^ b.s7);
}

// horizontal 3-tap max on packed row v, clamped by k: min(hmax3(v), k)
static __device__ __forceinline__ W8 hpass(W8 v, W8 k) {
    uint32_t lv = dpp_shr1(v.s7);
    uint32_t rv = dpp_shl1(v.s0);
    W8 m;
    m.s0 = pmin(pmax(pmax(v.s0, alignb(v.s0, lv)),   alignb(v.s1, v.s0)), k.s0);
    m.s1 = pmin(pmax(pmax(v.s1, alignb(v.s1, v.s0)), alignb(v.s2, v.s1)), k.s1);
    m.s2 = pmin(pmax(pmax(v.s2, alignb(v.s2, v.s1)), alignb(v.s3, v.s2)), k.s2);
    m.s3 = pmin(pmax(pmax(v.s3, alignb(v.s3, v.s2)), alignb(v.s4, v.s3)), k.s3);
    m.s4 = pmin(pmax(pmax(v.s4, alignb(v.s4, v.s3)), alignb(v.s5, v.s4)), k.s4);
    m.s5 = pmin(pmax(pmax(v.s5, alignb(v.s5, v.s4)), alignb(v.s6, v.s5)), k.s5);
    m.s6 = pmin(pmax(pmax(v.s6, alignb(v.s6, v.s5)), alignb(v.s7, v.s6)), k.s6);
    m.s7 = pmin(pmax(pmax(v.s7, alignb(v.s7, v.s6)), alignb(rv,   v.s7)), k.s7);
    return m;
}

__global__ __launch_bounds__(1024, 1) void hx_full(
    const float* __restrict__ img,   // f32 [128][256][256]
    const float* __restrict__ hh,    // f32 [128]
    float*       __restrict__ fout)  // f32 out
{
    // Parity halo-row buffers. A[p][g] = g's bottom row (read by g+1);
    // B[p][g] = g's top row (read by g-1). B[p][0] and A[p][63] dead ->
    // host the 3 convergence-flag slots.
    __shared__ uint32_t A[2][GROUPS][128];   // 65,536 B
    __shared__ uint32_t B[2][GROUPS][128];   // 65,536 B (total exactly 128 KiB)

    const int tid = threadIdx.x;
    const int seg = tid & 15;
    const int g   = tid >> 4;        // 64 groups x 4 rows = 256 rows (all useful)
    const int b   = blockIdx.x;      // one image per block
    const int sw  = seg * 8;

    uint32_t* f0p = &B[0][0][0];
    uint32_t* f1p = &B[1][0][0];
    uint32_t* f2p = &A[0][GROUPS - 1][0];
    if (tid == 0) { *f0p = 0; *f1p = 0; *f2p = 0; }
    uint32_t *pW = f0p, *pR = f2p, *pZ = f1p;  // t=0: write s0, read s2, reset s1

    // Fused init: rows 4g..4g+3 always in [0,256) -- no bounds checks.
    W8 m0, m1, m2, m3, k0, k1, k2, k3;
    const float hb = hh[b];
    {
        const size_t ib = ((size_t)b << 16) + ((size_t)(4 * g) << 8) + seg * 16;
        #pragma unroll
        for (int r = 0; r < 4; ++r) {
            const float4* src = reinterpret_cast<const float4*>(img + ib + ((size_t)r << 8));
            float4 fa = src[0], fb = src[1], fc = src[2], fd = src[3];
            W8 kv, mv;
            kv.s0 = pack2(fa.x, fa.y);       kv.s1 = pack2(fa.z, fa.w);
            kv.s2 = pack2(fb.x, fb.y);       kv.s3 = pack2(fb.z, fb.w);
            kv.s4 = pack2(fc.x, fc.y);       kv.s5 = pack2(fc.z, fc.w);
            kv.s6 = pack2(fd.x, fd.y);       kv.s7 = pack2(fd.z, fd.w);
            mv.s0 = pack2(fa.x-hb, fa.y-hb); mv.s1 = pack2(fa.z-hb, fa.w-hb);
            mv.s2 = pack2(fb.x-hb, fb.y-hb); mv.s3 = pack2(fb.z-hb, fb.w-hb);
            mv.s4 = pack2(fc.x-hb, fc.y-hb); mv.s5 = pack2(fc.z-hb, fc.w-hb);
            mv.s6 = pack2(fd.x-hb, fd.y-hb); mv.s7 = pack2(fd.z-hb, fd.w-hb);
            if (r == 0) { m0 = mv; k0 = kv; }
            else if (r == 1) { m1 = mv; k1 = kv; }
            else if (r == 2) { m2 = mv; k2 = kv; }
            else { m3 = mv; k3 = kv; }
        }
    }

    for (int t = 0; t < TITER; ++t) {
        const int p = t & 1;
        if (g < GROUPS - 1) st8(&A[p][g][sw], m3);   // A[p][63] = flag home
        if (g > 0)          st8(&B[p][g][sw], m0);   // B[p][0]  = flag home
        __syncthreads();                              // the ONLY barrier/iter
        if (t > 0 && *pR == 0) break;                 // uniform, exact
        W8 ab = (g > 0)          ? ld8(&A[p][g - 1][sw]) : wneg();
        W8 bl = (g < GROUPS - 1) ? ld8(&B[p][g + 1][sw]) : wneg();
        W8 t01 = wmax(m0, m1);
        W8 t12 = wmax(m1, m2);
        W8 t23 = wmax(m2, m3);
        W8 nm1 = hpass(wmax(t01, m2), k1);    // interior rows first
        W8 nm2 = hpass(wmax(t12, m3), k2);
        W8 v0  = wmax(ab, t01);
        W8 v3  = wmax(t23, bl);
        W8 nm0 = hpass(v0, k0);
        W8 nm3 = hpass(v3, k3);
        uint32_t ch = wdiff(nm0, m0) | wdiff(nm1, m1) |
                      wdiff(nm2, m2) | wdiff(nm3, m3);
        if (ch) *pW = 1;                      // racing 1s, uniform addr: OK
        if (tid == 0) *pZ = 0;                // slot (t+1)%3, next written t+1
        uint32_t* tp = pW; pW = pZ; pZ = pR; pR = tp;   // rotate slots
        m0 = nm0; m1 = nm1; m2 = nm2; m3 = nm3;
    }

    // write back all 4 rows as f32
    {
        const size_t ob = ((size_t)b << 16) + ((size_t)(4 * g) << 8) + seg * 16;
        #pragma unroll
        for (int r = 0; r < 4; ++r) {
            W8 mv = (r == 0) ? m0 : (r == 1) ? m1 : (r == 2) ? m2 : m3;
            float* orow = fout + ob + ((size_t)r << 8);
            h2 x, y; float4 f;
            x = __builtin_bit_cast(h2, mv.s0); y = __builtin_bit_cast(h2, mv.s1);
            f.x = (float)x.x; f.y = (float)x.y; f.z = (float)y.x; f.w = (float)y.y;
            reinterpret_cast<float4*>(orow)[0] = f;
            x = __builtin_bit_cast(h2, mv.s2); y = __builtin_bit_cast(h2, mv.s3);
            f.x = (float)x.x; f.y = (float)x.y; f.z = (float)y.x; f.w = (float)y.y;
            reinterpret_cast<float4*>(orow)[1] = f;
            x = __builtin_bit_cast(h2, mv.s4); y = __builtin_bit_cast(h2, mv.s5);
            f.x = (float)x.x; f.y = (float)x.y; f.z = (float)y.x; f.w = (float)y.y;
            reinterpret_cast<float4*>(orow)[2] = f;
            x = __builtin_bit_cast(h2, mv.s6); y = __builtin_bit_cast(h2, mv.s7);
            f.x = (float)x.x; f.y = (float)x.y; f.z = (float)y.x; f.w = (float)y.y;
            reinterpret_cast<float4*>(orow)[3] = f;
        }
    }
}

extern "C" void kernel_launch(void* const* d_in, const int* in_sizes, int n_in,
                              void* d_out, int out_size, void* d_ws, size_t ws_size,
                              hipStream_t stream) {
    const float* img = (const float*)d_in[0];
    const float* hh  = (const float*)d_in[1];
    hx_full<<<128, 1024, 0, stream>>>(img, hh, (float*)d_out);
}

// Round 25
// 124.602 us; speedup vs baseline: 2.1651x; 1.1952x over previous
//
#include <hip/hip_runtime.h>
#include <stdint.h>

// H-maxima: 128 iters of m = min(dilate3x3(m), img), marker0 = img - h.
// SINGLE LAUNCH (R24-proven): one block per image (128 blk x 1024 thr),
// 64 groups x 4 rows/thread, all 256 rows in registers, no halo/redundancy.
// 1 barrier/iter parity halo (A/B [2][64][128] = 128 KiB); block-exit flags
// in dead rows, 3-slot rotation; asm v_pk_max/min_f16.
// NEW vs R24: EXACT per-group activity skip. chg[q][g] = (m_g(gen q-parity)
// changed), stored in dead row A[q][63][8..73]. Group g skips compute at
// iter t iff chg[1-p][g-1,g,g+1]==0 (then F inputs unchanged -> output
// unchanged -- exact). Wave-uniform skip via __any (exec-masked lanes would
// still burn issue cycles). Group change-bit = wdiff OR-reduced by shfl_xor
// within the 16-lane group, single writer -> race-free; all chg accesses
// barrier-separated (write@t / read@t+1 / prior-read@t-1 cross barriers).

#define NEGPAIR 0xFBFFFBFFu   // fp16 -65504 x2 == -inf pad
#define TITER 128
#define GROUPS 64

typedef _Float16 h2  __attribute__((ext_vector_type(2)));
typedef __fp16   fh2 __attribute__((ext_vector_type(2)));

static __device__ __forceinline__ uint32_t pmax(uint32_t a, uint32_t b) {
    uint32_t r;
    asm("v_pk_max_f16 %0, %1, %2" : "=v"(r) : "v"(a), "v"(b));
    return r;
}
static __device__ __forceinline__ uint32_t pmin(uint32_t a, uint32_t b) {
    uint32_t r;
    asm("v_pk_min_f16 %0, %1, %2" : "=v"(r) : "v"(a), "v"(b));
    return r;
}
static __device__ __forceinline__ uint32_t alignb(uint32_t hi, uint32_t lo) {
    return __builtin_amdgcn_alignbit(hi, lo, 16);   // {lo.hi16, hi.lo16}
}
static __device__ __forceinline__ uint32_t pack2(float lo, float hi) {
    fh2 p = __builtin_amdgcn_cvt_pkrtz(lo, hi);
    return __builtin_bit_cast(uint32_t, p);
}
// seg s gets seg s-1's word; seg 0 gets NEGPAIR (16-lane DPP row == seg group)
static __device__ __forceinline__ uint32_t dpp_shr1(uint32_t s) {
    return (uint32_t)__builtin_amdgcn_update_dpp((int)NEGPAIR, (int)s, 0x111, 0xF, 0xF, false);
}
// seg s gets seg s+1's word; seg 15 gets NEGPAIR
static __device__ __forceinline__ uint32_t dpp_shl1(uint32_t s) {
    return (uint32_t)__builtin_amdgcn_update_dpp((int)NEGPAIR, (int)s, 0x101, 0xF, 0xF, false);
}

struct W8 { uint32_t s0, s1, s2, s3, s4, s5, s6, s7; };

static __device__ __forceinline__ W8 ld8(const uint32_t* p) {
    uint4 a = reinterpret_cast<const uint4*>(p)[0];
    uint4 b = reinterpret_cast<const uint4*>(p)[1];
    W8 w;
    w.s0 = a.x; w.s1 = a.y; w.s2 = a.z; w.s3 = a.w;
    w.s4 = b.x; w.s5 = b.y; w.s6 = b.z; w.s7 = b.w;
    return w;
}
static __device__ __forceinline__ void st8(uint32_t* p, W8 w) {
    reinterpret_cast<uint4*>(p)[0] = make_uint4(w.s0, w.s1, w.s2, w.s3);
    reinterpret_cast<uint4*>(p)[1] = make_uint4(w.s4, w.s5, w.s6, w.s7);
}
static __device__ __forceinline__ W8 wmax(W8 a, W8 b) {
    W8 r;
    r.s0 = pmax(a.s0, b.s0); r.s1 = pmax(a.s1, b.s1);
    r.s2 = pmax(a.s2, b.s2); r.s3 = pmax(a.s3, b.s3);
    r.s4 = pmax(a.s4, b.s4); r.s5 = pmax(a.s5, b.s5);
    r.s6 = pmax(a.s6, b.s6); r.s7 = pmax(a.s7, b.s7);
    return r;
}
static __device__ __forceinline__ W8 wneg() {
    W8 r;
    r.s0 = NEGPAIR; r.s1 = NEGPAIR; r.s2 = NEGPAIR; r.s3 = NEGPAIR;
    r.s4 = NEGPAIR; r.s5 = NEGPAIR; r.s6 = NEGPAIR; r.s7 = NEGPAIR;
    return r;
}
static __device__ __forceinline__ uint32_t wdiff(W8 a, W8 b) {
    return (a.s0 ^ b.s0) | (a.s1 ^ b.s1) | (a.s2 ^ b.s2) | (a.s3 ^ b.s3) |
           (a.s4 ^ b.s4) | (a.s5 ^ b.s5) | (a.s6 ^ b.s6) | (a.s7 ^ b.s7);
}

// horizontal 3-tap max on packed row v, clamped by k: min(hmax3(v), k)
static __device__ __forceinline__ W8 hpass(W8 v, W8 k) {
    uint32_t lv = dpp_shr1(v.s7);
    uint32_t rv = dpp_shl1(v.s0);
    W8 m;
    m.s0 = pmin(pmax(pmax(v.s0, alignb(v.s0, lv)),   alignb(v.s1, v.s0)), k.s0);
    m.s1 = pmin(pmax(pmax(v.s1, alignb(v.s1, v.s0)), alignb(v.s2, v.s1)), k.s1);
    m.s2 = pmin(pmax(pmax(v.s2, alignb(v.s2, v.s1)), alignb(v.s3, v.s2)), k.s2);
    m.s3 = pmin(pmax(pmax(v.s3, alignb(v.s3, v.s2)), alignb(v.s4, v.s3)), k.s3);
    m.s4 = pmin(pmax(pmax(v.s4, alignb(v.s4, v.s3)), alignb(v.s5, v.s4)), k.s4);
    m.s5 = pmin(pmax(pmax(v.s5, alignb(v.s5, v.s4)), alignb(v.s6, v.s5)), k.s5);
    m.s6 = pmin(pmax(pmax(v.s6, alignb(v.s6, v.s5)), alignb(v.s7, v.s6)), k.s6);
    m.s7 = pmin(pmax(pmax(v.s7, alignb(v.s7, v.s6)), alignb(rv,   v.s7)), k.s7);
    return m;
}

__global__ __launch_bounds__(1024, 1) void hx_full(
    const float* __restrict__ img,   // f32 [128][256][256]
    const float* __restrict__ hh,    // f32 [128]
    float*       __restrict__ fout)  // f32 out
{
    // Parity halo-row buffers. A[p][g] = g's bottom row (read by g+1);
    // B[p][g] = g's top row (read by g-1). Dead rows B[p][0], A[p][63] host
    // the 3 exit-flag slots (word 0) and the chg bitmaps (A[p][63][8..73]).
    __shared__ uint32_t A[2][GROUPS][128];   // 65,536 B
    __shared__ uint32_t B[2][GROUPS][128];   // 65,536 B (total exactly 128 KiB)

    const int tid = threadIdx.x;
    const int seg = tid & 15;
    const int g   = tid >> 4;        // 64 groups x 4 rows = 256 rows
    const int b   = blockIdx.x;      // one image per block
    const int sw  = seg * 8;

    uint32_t* f0p = &B[0][0][0];
    uint32_t* f1p = &B[1][0][0];
    uint32_t* f2p = &A[0][GROUPS - 1][0];
    uint32_t* cg0 = &A[0][GROUPS - 1][8];   // chg parity 0: entries [0..65]
    uint32_t* cg1 = &A[1][GROUPS - 1][8];   // chg parity 1
    if (tid == 0) { *f0p = 0; *f1p = 0; *f2p = 0; }
    if (tid < 66) {                         // pad entries 0,65 = 0; groups = 1
        uint32_t v = (tid >= 1 && tid <= 64) ? 1u : 0u;
        cg0[tid] = v; cg1[tid] = v;
    }
    uint32_t *pW = f0p, *pR = f2p, *pZ = f1p;  // t=0: write s0, read s2, reset s1

    // Fused init: rows 4g..4g+3 always in [0,256) -- no bounds checks.
    W8 m0, m1, m2, m3, k0, k1, k2, k3;
    const float hb = hh[b];
    {
        const size_t ib = ((size_t)b << 16) + ((size_t)(4 * g) << 8) + seg * 16;
        #pragma unroll
        for (int r = 0; r < 4; ++r) {
            const float4* src = reinterpret_cast<const float4*>(img + ib + ((size_t)r << 8));
            float4 fa = src[0], fb = src[1], fc = src[2], fd = src[3];
            W8 kv, mv;
            kv.s0 = pack2(fa.x, fa.y);       kv.s1 = pack2(fa.z, fa.w);
            kv.s2 = pack2(fb.x, fb.y);       kv.s3 = pack2(fb.z, fb.w);
            kv.s4 = pack2(fc.x, fc.y);       kv.s5 = pack2(fc.z, fc.w);
            kv.s6 = pack2(fd.x, fd.y);       kv.s7 = pack2(fd.z, fd.w);
            mv.s0 = pack2(fa.x-hb, fa.y-hb); mv.s1 = pack2(fa.z-hb, fa.w-hb);
            mv.s2 = pack2(fb.x-hb, fb.y-hb); mv.s3 = pack2(fb.z-hb, fb.w-hb);
            mv.s4 = pack2(fc.x-hb, fc.y-hb); mv.s5 = pack2(fc.z-hb, fc.w-hb);
            mv.s6 = pack2(fd.x-hb, fd.y-hb); mv.s7 = pack2(fd.z-hb, fd.w-hb);
            if (r == 0) { m0 = mv; k0 = kv; }
            else if (r == 1) { m1 = mv; k1 = kv; }
            else if (r == 2) { m2 = mv; k2 = kv; }
            else { m3 = mv; k3 = kv; }
        }
    }

    for (int t = 0; t < TITER; ++t) {
        const int p = t & 1;
        if (g < GROUPS - 1) st8(&A[p][g][sw], m3);
        if (g > 0)          st8(&B[p][g][sw], m0);
        __syncthreads();                              // the ONLY barrier/iter
        if (t > 0 && *pR == 0) break;                 // uniform, exact
        const uint32_t* cgR = p ? cg0 : cg1;   // gen-t changes (written iter t-1)
        uint32_t*       cgW = p ? cg1 : cg0;   // gen-(t+1) changes (read iter t+1)
        int active = (cgR[g] | cgR[g + 1] | cgR[g + 2]) != 0;
        if (__any(active)) {
            W8 ab = (g > 0)          ? ld8(&A[p][g - 1][sw]) : wneg();
            W8 bl = (g < GROUPS - 1) ? ld8(&B[p][g + 1][sw]) : wneg();
            W8 t01 = wmax(m0, m1);
            W8 t12 = wmax(m1, m2);
            W8 t23 = wmax(m2, m3);
            W8 nm1 = hpass(wmax(t01, m2), k1);
            W8 nm2 = hpass(wmax(t12, m3), k2);
            W8 v0  = wmax(ab, t01);
            W8 v3  = wmax(t23, bl);
            W8 nm0 = hpass(v0, k0);
            W8 nm3 = hpass(v3, k3);
            uint32_t ch = wdiff(nm0, m0) | wdiff(nm1, m1) |
                          wdiff(nm2, m2) | wdiff(nm3, m3);
            uint32_t c = ch;                   // OR across the 16-lane group
            c |= __shfl_xor(c, 1); c |= __shfl_xor(c, 2);
            c |= __shfl_xor(c, 4); c |= __shfl_xor(c, 8);
            if (seg == 0) cgW[g + 1] = c ? 1u : 0u;   // single writer/group
            if (ch) *pW = 1;                   // racing 1s, uniform addr: OK
            m0 = nm0; m1 = nm1; m2 = nm2; m3 = nm3;
        } else {
            if (seg == 0) cgW[g + 1] = 0;      // state provably unchanged
        }
        if (tid == 0) *pZ = 0;                 // slot (t+1)%3
        uint32_t* tp = pW; pW = pZ; pZ = pR; pR = tp;   // rotate slots
    }

    // write back all 4 rows as f32
    {
        const size_t ob = ((size_t)b << 16) + ((size_t)(4 * g) << 8) + seg * 16;
        #pragma unroll
        for (int r = 0; r < 4; ++r) {
            W8 mv = (r == 0) ? m0 : (r == 1) ? m1 : (r == 2) ? m2 : m3;
            float* orow = fout + ob + ((size_t)r << 8);
            h2 x, y; float4 f;
            x = __builtin_bit_cast(h2, mv.s0); y = __builtin_bit_cast(h2, mv.s1);
            f.x = (float)x.x; f.y = (float)x.y; f.z = (float)y.x; f.w = (float)y.y;
            reinterpret_cast<float4*>(orow)[0] = f;
            x = __builtin_bit_cast(h2, mv.s2); y = __builtin_bit_cast(h2, mv.s3);
            f.x = (float)x.x; f.y = (float)x.y; f.z = (float)y.x; f.w = (float)y.y;
            reinterpret_cast<float4*>(orow)[1] = f;
            x = __builtin_bit_cast(h2, mv.s4); y = __builtin_bit_cast(h2, mv.s5);
            f.x = (float)x.x; f.y = (float)x.y; f.z = (float)y.x; f.w = (float)y.y;
            reinterpret_cast<float4*>(orow)[2] = f;
            x = __builtin_bit_cast(h2, mv.s6); y = __builtin_bit_cast(h2, mv.s7);
            f.x = (float)x.x; f.y = (float)x.y; f.z = (float)y.x; f.w = (float)y.y;
            reinterpret_cast<float4*>(orow)[3] = f;
        }
    }
}

extern "C" void kernel_launch(void* const* d_in, const int* in_sizes, int n_in,
                              void* d_out, int out_size, void* d_ws, size_t ws_size,
                              hipStream_t stream) {
    const float* img = (const float*)d_in[0];
    const float* hh  = (const float*)d_in[1];
    hx_full<<<128, 1024, 0, stream>>>(img, hh, (float*)d_out);
}